// Round 3
// baseline (291.376 us; speedup 1.0000x reference)
//
#include <hip/hip_runtime.h>
#include <hip/hip_bf16.h>

#define NB   8
#define NS   5
#define NQ   128
#define TT   16
#define DD   2048
#define NROW 1024          // B*nq
#define NSROW (NB * NS * TT)    // 640 supp rows
#define NQROW (NROW * TT)       // 16384 query rows
#define NRTOT (NSROW + NQROW)   // 17024
#define LAMI 10.0f         // 1/LAM
#define LAMF 0.1f

typedef __attribute__((ext_vector_type(8))) short  short8;
typedef __attribute__((ext_vector_type(4))) float  float4v;

// pack two f32 -> bf16x2 (RNE)
static __device__ __forceinline__ unsigned int f2bf2(float x, float y) {
    union { float f; unsigned int u; } a, b; a.f = x; b.f = y;
    unsigned int ra = a.u + 0x7fffu + ((a.u >> 16) & 1u);
    unsigned int rb = b.u + 0x7fffu + ((b.u >> 16) & 1u);
    return (ra >> 16) | (rb & 0xffff0000u);
}

static __device__ __forceinline__ float lse2f(float x, float y) {
    float mx = fmaxf(x, y), mn = fminf(x, y);
    return mx + __logf(1.0f + __expf(mn - mx));
}

// One wave per row: f32 -> bf16 convert + row sum-of-squares.
__global__ __launch_bounds__(256) void
preproc_kernel(const float* __restrict__ supp, const float* __restrict__ query,
               unsigned short* __restrict__ suppBf, unsigned short* __restrict__ queryBf,
               float* __restrict__ suppSq, float* __restrict__ querySq)
{
    const int wave = threadIdx.x >> 6, lane = threadIdx.x & 63;
    const int row = blockIdx.x * 4 + wave;           // 0..17023
    const float* src; unsigned short* dst; float* sqp;
    if (row < NSROW) {
        src = supp + (size_t)row * DD;  dst = suppBf + (size_t)row * DD;  sqp = suppSq + row;
    } else {
        int r = row - NSROW;
        src = query + (size_t)r * DD;   dst = queryBf + (size_t)r * DD;   sqp = querySq + r;
    }
    float ss = 0.f;
    #pragma unroll
    for (int i = 0; i < 8; ++i) {
        float4 v = *reinterpret_cast<const float4*>(src + i * 256 + lane * 4);
        uint2 pv = { f2bf2(v.x, v.y), f2bf2(v.z, v.w) };
        *reinterpret_cast<uint2*>(dst + i * 256 + lane * 4) = pv;
        ss += v.x * v.x + v.y * v.y + v.z * v.z + v.w * v.w;
    }
    ss += __shfl_xor(ss, 32, 64);
    ss += __shfl_xor(ss, 16, 64);
    ss += __shfl_xor(ss, 8, 64);
    ss += __shfl_xor(ss, 4, 64);
    ss += __shfl_xor(ss, 2, 64);
    ss += __shfl_xor(ss, 1, 64);
    if (lane == 0) *sqp = ss;
}

// One block per (b,q); wave s computes the 16x16 dist tile via direct-from-global
// bf16 MFMA fragments (no LDS staging, no K-loop barriers), then fused DTW.
__global__ __launch_bounds__(320) void
dist_dtw_kernel(const unsigned short* __restrict__ suppBf, const unsigned short* __restrict__ queryBf,
                const float* __restrict__ suppSq, const float* __restrict__ querySq,
                float* __restrict__ out_tam, float* __restrict__ t1w, float* __restrict__ t2w)
{
    __shared__ float ssq[96];
    __shared__ float distS[NS][TT][TT];
    __shared__ float tamv[16];

    const int tid  = threadIdx.x;
    const int blk  = blockIdx.x;          // b*128 + q
    const int wave = tid >> 6;            // 0..4 == s
    const int lane = tid & 63;
    const int fr   = lane & 15;
    const int quad = lane >> 4;

    if (tid < 80)      ssq[tid] = suppSq[(blk >> 7) * (NS * TT) + tid];
    else if (tid < 96) ssq[tid] = querySq[blk * TT + (tid - 80)];

    const unsigned short* ap =
        suppBf + ((size_t)((blk >> 7) * NS + wave) * TT + fr) * DD + quad * 8;
    const unsigned short* bp =
        queryBf + ((size_t)blk * TT + fr) * DD + quad * 8;

    float4v acc0 = {0.f, 0.f, 0.f, 0.f}, acc1 = {0.f, 0.f, 0.f, 0.f};
    #pragma unroll 8
    for (int k = 0; k < 64; k += 2) {
        short8 a0 = *reinterpret_cast<const short8*>(ap + k * 32);
        short8 b0 = *reinterpret_cast<const short8*>(bp + k * 32);
        short8 a1 = *reinterpret_cast<const short8*>(ap + k * 32 + 32);
        short8 b1 = *reinterpret_cast<const short8*>(bp + k * 32 + 32);
        acc0 = __builtin_amdgcn_mfma_f32_16x16x32_bf16(a0, b0, acc0, 0, 0, 0);
        acc1 = __builtin_amdgcn_mfma_f32_16x16x32_bf16(a1, b1, acc1, 0, 0, 0);
    }
    __syncthreads();   // ssq ready

    // epilogue: dist[s][l][m] = 1 - dot / max(||s_l||*||q_m||, eps)
    {
        float qn = sqrtf(ssq[80 + fr]);
        #pragma unroll
        for (int r = 0; r < 4; ++r) {
            int l = quad * 4 + r;
            float denom = fmaxf(sqrtf(ssq[wave * 16 + l]) * qn, 1e-8f);
            distS[wave][l][fr] = 1.0f - (acc0[r] + acc1[r]) / denom;
        }
    }
    __syncthreads();

    // DTW: anti-diagonal wavefront. wave w = support s; lanes 0..17 dir=0, 32..49 dir=1.
    if ((lane & 31) <= 17) {
        const int g   = lane & 31;
        const int dir = lane >> 5;
        const int s   = wave;
        float val = 0.f, vprev = 0.f;
        #pragma unroll
        for (int t = 1; t <= 32; ++t) {
            float left = __shfl_up(val,   1, 32);  // (l,   g-1)
            float diag = __shfl_up(vprev, 1, 32);  // (l-1, g-1)
            int l = t - g;
            if (g >= 1 && l >= 0 && l <= 15) {
                float d = 0.f;
                if (g <= 16) d = dir ? distS[s][15 - l][16 - g] : distS[s][l][g - 1];
                float nv;
                if (l == 0) {
                    nv = left + d;
                } else if (g == 1 || g == 17) {
                    nv = -LAMF * lse2f(lse2f(-diag * LAMI, -left * LAMI), -val * LAMI) + d;
                } else {
                    float lo2 = fminf(diag, left), hi2 = fmaxf(diag, left);
                    nv = lo2 - LAMF * __logf(1.0f + __expf((lo2 - hi2) * LAMI)) + d;
                }
                vprev = val; val = nv;
            }
        }
        if (g == 17) tamv[s * 2 + dir] = val;
    }
    __syncthreads();

    if (tid < NS) {
        float t1 = tamv[2 * tid], t2 = tamv[2 * tid + 1];
        int n = blk * NS + tid;
        t1w[n] = t1;
        t2w[n] = t2;
        out_tam[n] = 0.5f * (t1 + t2);
    }
}

__global__ __launch_bounds__(1024) void
loss_kernel(const float* __restrict__ t1w, const float* __restrict__ t2w,
            const int* __restrict__ ys, float* __restrict__ out)
{
    __shared__ float red[16];
    const int row = threadIdx.x;

    float t1[NS], t2[NS];
    #pragma unroll
    for (int s = 0; s < NS; ++s) { t1[s] = t1w[row * NS + s]; t2[s] = t2w[row * NS + s]; }
    const int y = ys[row];

    float mx1 = -t1[0], mx2 = -t2[0];
    #pragma unroll
    for (int s = 1; s < NS; ++s) { mx1 = fmaxf(mx1, -t1[s]); mx2 = fmaxf(mx2, -t2[s]); }
    float s1 = 0.f, s2 = 0.f;
    #pragma unroll
    for (int s = 0; s < NS; ++s) { s1 += __expf(-t1[s] - mx1); s2 += __expf(-t2[s] - mx2); }
    float lse1  = mx1 + __logf(s1);
    float lse2v = mx2 + __logf(s2);

    float ty1 = t1[0], ty2 = t2[0];
    #pragma unroll
    for (int s = 1; s < NS; ++s) { if (y == s) { ty1 = t1[s]; ty2 = t2[s]; } }

    float c = 0.5f * ((lse1 + ty1) + (lse2v + ty2));

    #pragma unroll
    for (int off = 32; off >= 1; off >>= 1) c += __shfl_down(c, off, 64);
    if ((row & 63) == 0) red[row >> 6] = c;
    __syncthreads();
    if (row == 0) {
        float tot = 0.f;
        #pragma unroll
        for (int i = 0; i < 16; ++i) tot += red[i];
        out[0] = tot * (1.0f / (float)NROW);
    }
}

extern "C" void kernel_launch(void* const* d_in, const int* in_sizes, int n_in,
                              void* d_out, int out_size, void* d_ws, size_t ws_size,
                              hipStream_t stream) {
    const float* supp  = (const float*)d_in[0];
    const float* query = (const float*)d_in[1];
    const int*   ys    = (const int*)d_in[2];
    float* out = (float*)d_out;

    // ws layout (all 16B-aligned offsets)
    float* t1w     = (float*)d_ws;                       // 5120 f32
    float* t2w     = t1w + NROW * NS;                    // 5120 f32
    float* suppSq  = t2w + NROW * NS;                    // 640 f32
    float* querySq = suppSq + NSROW;                     // 16384 f32
    unsigned short* suppBf  = (unsigned short*)(querySq + NQROW);   // 640*2048 bf16
    unsigned short* queryBf = suppBf + (size_t)NSROW * DD;          // 16384*2048 bf16

    preproc_kernel<<<NRTOT / 4, 256, 0, stream>>>(supp, query, suppBf, queryBf, suppSq, querySq);
    dist_dtw_kernel<<<NROW, 320, 0, stream>>>(suppBf, queryBf, suppSq, querySq, out + 1, t1w, t2w);
    loss_kernel<<<1, 1024, 0, stream>>>(t1w, t2w, ys, out);
}

// Round 4
// 252.545 us; speedup vs baseline: 1.1538x; 1.1538x over previous
//
#include <hip/hip_runtime.h>
#include <hip/hip_bf16.h>

#define NB   8
#define NS   5
#define NQ   128
#define TT   16
#define DD   2048
#define NROW 1024               // B*nq
#define NSROW (NB * NS * TT)    // 640 supp rows
#define LDB  2056               // B-tile LDS row stride in shorts (+8 pad -> 2-way only)
#define LAMI 10.0f
#define LAMF 0.1f

typedef __attribute__((ext_vector_type(8))) short  short8;
typedef __attribute__((ext_vector_type(4))) float  float4v;

// pack two f32 -> bf16x2 (RNE)
static __device__ __forceinline__ unsigned int f2bf2(float x, float y) {
    union { float f; unsigned int u; } a, b; a.f = x; b.f = y;
    unsigned int ra = a.u + 0x7fffu + ((a.u >> 16) & 1u);
    unsigned int rb = b.u + 0x7fffu + ((b.u >> 16) & 1u);
    return (ra >> 16) | (rb & 0xffff0000u);
}

static __device__ __forceinline__ float lse2f(float x, float y) {
    float mx = fmaxf(x, y), mn = fminf(x, y);
    return mx + __logf(1.0f + __expf(mn - mx));
}

// supp only: f32 -> bf16 + row sum-of-squares. One wave per row (640 rows).
__global__ __launch_bounds__(256) void
preproc_supp(const float* __restrict__ supp, unsigned short* __restrict__ suppBf,
             float* __restrict__ suppSq)
{
    const int wave = threadIdx.x >> 6, lane = threadIdx.x & 63;
    const int row = blockIdx.x * 4 + wave;           // 0..639
    const float* src = supp + (size_t)row * DD;
    unsigned short* dst = suppBf + (size_t)row * DD;
    float ss = 0.f;
    #pragma unroll
    for (int i = 0; i < 8; ++i) {
        float4 v = *reinterpret_cast<const float4*>(src + i * 256 + lane * 4);
        uint2 pv = { f2bf2(v.x, v.y), f2bf2(v.z, v.w) };
        *reinterpret_cast<uint2*>(dst + i * 256 + lane * 4) = pv;
        ss += v.x * v.x + v.y * v.y + v.z * v.z + v.w * v.w;
    }
    #pragma unroll
    for (int off = 32; off >= 1; off >>= 1) ss += __shfl_xor(ss, off, 64);
    if (lane == 0) suppSq[row] = ss;
}

// One block per (b,q). Phase 1: 8 waves stage the 16x2048 query tile f32->bf16 LDS
// (query read ONCE from HBM, never written back). Phase 2: waves 0..4 (=s) MFMA with
// A direct from L2-resident suppBf, B from LDS; no K-loop barriers. Then fused DTW.
__global__ __launch_bounds__(512, 4) void
dist_dtw_kernel(const unsigned short* __restrict__ suppBf, const float* __restrict__ suppSq,
                const float* __restrict__ query,
                float* __restrict__ out_tam, float* __restrict__ t1w, float* __restrict__ t2w)
{
    __shared__ __align__(16) unsigned short sB[TT * LDB];   // 65792 B
    __shared__ float ssq[96];
    __shared__ float distS[NS][TT][TT];
    __shared__ float tamv[16];

    const int tid  = threadIdx.x;
    const int blk  = blockIdx.x;          // b*128 + q
    const int wave = tid >> 6;            // 0..7 (0..4 = s)
    const int lane = tid & 63;
    const int fr   = lane & 15;
    const int quad = lane >> 4;

    // ---- phase 1: stage query tile ----
    {
        const int r = tid >> 5;           // 0..15
        const int c = tid & 31;           // float4 column base
        const float* src = query + (size_t)(blk * TT + r) * DD;
        float ss = 0.f;
        #pragma unroll
        for (int i = 0; i < 16; ++i) {
            float4 v = *reinterpret_cast<const float4*>(src + (c + i * 32) * 4);
            uint2 pv = { f2bf2(v.x, v.y), f2bf2(v.z, v.w) };
            *reinterpret_cast<uint2*>(&sB[r * LDB + (c + i * 32) * 4]) = pv;
            ss += v.x * v.x + v.y * v.y + v.z * v.z + v.w * v.w;
        }
        #pragma unroll
        for (int off = 16; off >= 1; off >>= 1) ss += __shfl_xor(ss, off, 32);
        if ((tid & 31) == 0) ssq[80 + r] = ss;
        if (tid < 80) ssq[tid] = suppSq[(blk >> 7) * (NS * TT) + tid];
    }
    __syncthreads();

    // ---- phase 2: MFMA, A from global (L2-hot), B from LDS ----
    float4v acc0 = {0.f, 0.f, 0.f, 0.f}, acc1 = {0.f, 0.f, 0.f, 0.f};
    if (wave < NS) {
        const unsigned short* ap =
            suppBf + ((size_t)((blk >> 7) * NS + wave) * TT + fr) * DD + quad * 8;
        const unsigned short* bp = &sB[fr * LDB + quad * 8];
        #pragma unroll 8
        for (int k = 0; k < 64; k += 2) {
            short8 a0 = *reinterpret_cast<const short8*>(ap + k * 32);
            short8 a1 = *reinterpret_cast<const short8*>(ap + k * 32 + 32);
            short8 b0 = *reinterpret_cast<const short8*>(bp + k * 32);
            short8 b1 = *reinterpret_cast<const short8*>(bp + k * 32 + 32);
            acc0 = __builtin_amdgcn_mfma_f32_16x16x32_bf16(a0, b0, acc0, 0, 0, 0);
            acc1 = __builtin_amdgcn_mfma_f32_16x16x32_bf16(a1, b1, acc1, 0, 0, 0);
        }
        // epilogue: dist[s][l][m] = 1 - dot / max(||s_l||*||q_m||, eps)
        float qn = sqrtf(ssq[80 + fr]);
        #pragma unroll
        for (int r = 0; r < 4; ++r) {
            int l = quad * 4 + r;
            float denom = fmaxf(sqrtf(ssq[wave * 16 + l]) * qn, 1e-8f);
            distS[wave][l][fr] = 1.0f - (acc0[r] + acc1[r]) / denom;
        }
    }
    __syncthreads();

    // ---- DTW: anti-diagonal wavefront; wave s, lanes 0..17 dir=0, 32..49 dir=1 ----
    if (wave < NS && (lane & 31) <= 17) {
        const int g   = lane & 31;
        const int dir = lane >> 5;
        const int s   = wave;
        float val = 0.f, vprev = 0.f;
        #pragma unroll
        for (int t = 1; t <= 32; ++t) {
            float left = __shfl_up(val,   1, 32);
            float diag = __shfl_up(vprev, 1, 32);
            int l = t - g;
            if (g >= 1 && l >= 0 && l <= 15) {
                float d = 0.f;
                if (g <= 16) d = dir ? distS[s][15 - l][16 - g] : distS[s][l][g - 1];
                float nv;
                if (l == 0) {
                    nv = left + d;
                } else if (g == 1 || g == 17) {
                    nv = -LAMF * lse2f(lse2f(-diag * LAMI, -left * LAMI), -val * LAMI) + d;
                } else {
                    float lo2 = fminf(diag, left), hi2 = fmaxf(diag, left);
                    nv = lo2 - LAMF * __logf(1.0f + __expf((lo2 - hi2) * LAMI)) + d;
                }
                vprev = val; val = nv;
            }
        }
        if (g == 17) tamv[s * 2 + dir] = val;
    }
    __syncthreads();

    if (tid < NS) {
        float t1 = tamv[2 * tid], t2 = tamv[2 * tid + 1];
        int n = blk * NS + tid;
        t1w[n] = t1;
        t2w[n] = t2;
        out_tam[n] = 0.5f * (t1 + t2);
    }
}

__global__ __launch_bounds__(1024) void
loss_kernel(const float* __restrict__ t1w, const float* __restrict__ t2w,
            const int* __restrict__ ys, float* __restrict__ out)
{
    __shared__ float red[16];
    const int row = threadIdx.x;

    float t1[NS], t2[NS];
    #pragma unroll
    for (int s = 0; s < NS; ++s) { t1[s] = t1w[row * NS + s]; t2[s] = t2w[row * NS + s]; }
    const int y = ys[row];

    float mx1 = -t1[0], mx2 = -t2[0];
    #pragma unroll
    for (int s = 1; s < NS; ++s) { mx1 = fmaxf(mx1, -t1[s]); mx2 = fmaxf(mx2, -t2[s]); }
    float s1 = 0.f, s2 = 0.f;
    #pragma unroll
    for (int s = 0; s < NS; ++s) { s1 += __expf(-t1[s] - mx1); s2 += __expf(-t2[s] - mx2); }
    float lse1  = mx1 + __logf(s1);
    float lse2v = mx2 + __logf(s2);

    float ty1 = t1[0], ty2 = t2[0];
    #pragma unroll
    for (int s = 1; s < NS; ++s) { if (y == s) { ty1 = t1[s]; ty2 = t2[s]; } }

    float c = 0.5f * ((lse1 + ty1) + (lse2v + ty2));

    #pragma unroll
    for (int off = 32; off >= 1; off >>= 1) c += __shfl_down(c, off, 64);
    if ((row & 63) == 0) red[row >> 6] = c;
    __syncthreads();
    if (row == 0) {
        float tot = 0.f;
        #pragma unroll
        for (int i = 0; i < 16; ++i) tot += red[i];
        out[0] = tot * (1.0f / (float)NROW);
    }
}

extern "C" void kernel_launch(void* const* d_in, const int* in_sizes, int n_in,
                              void* d_out, int out_size, void* d_ws, size_t ws_size,
                              hipStream_t stream) {
    const float* supp  = (const float*)d_in[0];
    const float* query = (const float*)d_in[1];
    const int*   ys    = (const int*)d_in[2];
    float* out = (float*)d_out;

    float* t1w    = (float*)d_ws;                              // 5120 f32
    float* t2w    = t1w + NROW * NS;                           // 5120 f32
    float* suppSq = t2w + NROW * NS;                           // 640 f32
    unsigned short* suppBf = (unsigned short*)(suppSq + NSROW);// 640*2048 bf16

    preproc_supp<<<NSROW / 4, 256, 0, stream>>>(supp, suppBf, suppSq);
    dist_dtw_kernel<<<NROW, 512, 0, stream>>>(suppBf, suppSq, query, out + 1, t1w, t2w);
    loss_kernel<<<1, 1024, 0, stream>>>(t1w, t2w, ys, out);
}